// Round 10
// baseline (205.696 us; speedup 1.0000x reference)
//
#include <hip/hip_runtime.h>

// B=2, C=256, H=W=64, P=3 -> Hp=Wp=62, Np=3844.
// X = A^T B via f16 MFMA hi/lo split (K=768), stored TILE-MAJOR.
// GEMM: 256x256 tile, BK=64, 8 waves, 4 phases/kt, counted vmcnt (round-7
// schedule) + swapped-operand MFMA -> float4 epilogue stores (round-9).
// corr: DIAGONAL-CHUNKED blocks (d, chunk of 8 pi): rolling 3-tile LDS ring,
// one new tile staged per step (2.3x less X traffic, strip-local L2 reuse).

typedef _Float16 half8 __attribute__((ext_vector_type(8)));
typedef float floatx4 __attribute__((ext_vector_type(4)));
typedef __attribute__((address_space(1))) const void gv_t;
typedef __attribute__((address_space(3))) void lv_t;

// ---------------------------------------------------------------------------
// prep: per-pixel L2 norm + f16 hi/lo split + pack [pix][768] with 4-slot XOR
// pre-swizzle. 4 threads per pixel (c-quarters).
__global__ void prep_kernel(const float* __restrict__ df1, const float* __restrict__ df2,
                            _Float16* __restrict__ Apack, _Float16* __restrict__ Bpack) {
  __shared__ float red[256];
  const int tid = threadIdx.x, q = tid >> 6, lane = tid & 63;
  int g = blockIdx.x * 64 + lane;           // pixel-task 0..16383
  int pix = g & 4095;
  int bm = g >> 12;
  int b = bm >> 1, m = bm & 1;              // m=0: df1 -> Bpack, m=1: df2 -> Apack
  const float* src = (m ? df2 : df1) + (size_t)b * 1048576 + pix;

  float ss = 0.f;
  for (int c = q * 64; c < q * 64 + 64; ++c) {
    float v = src[(size_t)c * 4096];
    ss += v * v;
  }
  red[tid] = ss;
  __syncthreads();
  float tot = red[lane] + red[lane + 64] + red[lane + 128] + red[lane + 192];
  float sc = 1.f / fmaxf(sqrtf(tot), 1e-12f);

  _Float16* dst = (m ? Apack : Bpack) + (size_t)b * 3145728 + (size_t)pix * 768;
  const int swz = (pix >> 1) & 3;

  for (int c0 = q * 64; c0 < q * 64 + 64; c0 += 8) {
    half8 hi, lo;
#pragma unroll
    for (int j = 0; j < 8; ++j) {
      float v = src[(size_t)(c0 + j) * 4096] * sc;
      _Float16 h = (_Float16)v;
      hi[j] = h;
      lo[j] = (_Float16)(4096.f * (v - (float)h));
    }
    int o = (c0 >> 3) & 31;
    int oS = (o & ~3) | ((o & 3) ^ swz);
    if (m) {  // A = [hi | lo | hi]
      *(half8*)(dst + oS * 8) = hi;
      *(half8*)(dst + 256 + oS * 8) = lo;
      *(half8*)(dst + 512 + oS * 8) = hi;
    } else {  // B = [lo | hi | hi]
      *(half8*)(dst + oS * 8) = lo;
      *(half8*)(dst + 256 + oS * 8) = hi;
      *(half8*)(dst + 512 + oS * 8) = hi;
    }
  }
}

// ---------------------------------------------------------------------------
__global__ __launch_bounds__(512, 2) void gemm_mfma(const _Float16* __restrict__ A,
                                                    const _Float16* __restrict__ B,
                                                    float* __restrict__ X) {
  __shared__ _Float16 As[2][2][256][32];    // [buf][khalf][row][32 f16] = 64 KB
  __shared__ _Float16 Bs[2][2][256][32];    // 64 KB

  int bid = blockIdx.x & 255;               // XCD swizzle
  int swb = (bid & 7) * 32 + (bid >> 3);
  int bx = swb & 15, by = swb >> 4;
  const int u0 = by << 8, v0 = bx << 8;

  const int tid = threadIdx.x, lane = tid & 63, wid = tid >> 6;
  const int wr = wid >> 2, wc = wid & 3;    // 2 x 4 waves; per-wave out 128x64
  const int frow = lane & 15, fhi = lane >> 4;
  const int fsw = (lane >> 1) & 3;

  floatx4 acc[8][4];
#pragma unroll
  for (int i = 0; i < 8; ++i)
#pragma unroll
    for (int j = 0; j < 4; ++j) acc[i][j] = (floatx4){0.f, 0.f, 0.f, 0.f};

  const _Float16* Abase = A + (size_t)u0 * 768;
  const _Float16* Bbase = B + (size_t)v0 * 768;

#define STG(OPB, LDSB, kt, kh)                                                \
  {                                                                           \
    _Pragma("unroll") for (int i_ = 0; i_ < 2; ++i_) {                        \
      int c_ = i_ * 512 + tid;                                                \
      int r_ = c_ >> 2, s_ = c_ & 3;                                          \
      __builtin_amdgcn_global_load_lds(                                       \
          (gv_t*)(OPB + (size_t)r_ * 768 + (kt) * 64 + (kh) * 32 + s_ * 8),   \
          (lv_t*)(&LDSB[(kt) & 1][kh][0][0] + c_ * 8), 16, 0, 0);             \
    }                                                                         \
  }

  STG(Abase, As, 0, 0); STG(Bbase, Bs, 0, 0);
  STG(Abase, As, 0, 1); STG(Bbase, Bs, 0, 1);
  STG(Abase, As, 1, 0); STG(Bbase, Bs, 1, 0);
  STG(Abase, As, 1, 1); STG(Bbase, Bs, 1, 1);
  asm volatile("s_waitcnt vmcnt(12)" ::: "memory");
  __builtin_amdgcn_sched_barrier(0);
  __builtin_amdgcn_s_barrier();

  half8 bf[4];

  for (int kt = 0; kt < 12; ++kt) {
    const int buf = kt & 1;
    const _Float16* LA0 = &As[buf][0][0][0];
    const _Float16* LB0 = &Bs[buf][0][0][0];
    const _Float16* LA1 = &As[buf][1][0][0];
    const _Float16* LB1 = &Bs[buf][1][0][0];
    half8 af[4];

    // ---------- P1 ----------
#pragma unroll
    for (int g = 0; g < 4; ++g)
      bf[g] = *(const half8*)(LB0 + (wc * 64 + g * 16 + frow) * 32 + ((fhi ^ fsw)) * 8);
#pragma unroll
    for (int f = 0; f < 4; ++f)
      af[f] = *(const half8*)(LA0 + (wr * 128 + f * 16 + frow) * 32 + ((fhi ^ fsw)) * 8);
    if (kt >= 1 && kt <= 10) STG(Abase, As, kt + 1, 1);
    __builtin_amdgcn_sched_barrier(0);
    __builtin_amdgcn_s_barrier();
    asm volatile("s_waitcnt lgkmcnt(0)" ::: "memory");
    __builtin_amdgcn_sched_barrier(0);
    __builtin_amdgcn_s_setprio(1);
#pragma unroll
    for (int f = 0; f < 4; ++f)
#pragma unroll
      for (int g = 0; g < 4; ++g)
        acc[f][g] = __builtin_amdgcn_mfma_f32_16x16x32_f16(bf[g], af[f], acc[f][g], 0, 0, 0);
    __builtin_amdgcn_s_setprio(0);
    __builtin_amdgcn_sched_barrier(0);
    __builtin_amdgcn_s_barrier();

    // ---------- P2 ----------
#pragma unroll
    for (int f = 0; f < 4; ++f)
      af[f] = *(const half8*)(LA0 + (wr * 128 + 64 + f * 16 + frow) * 32 + ((fhi ^ fsw)) * 8);
    if (kt >= 1 && kt <= 10) STG(Bbase, Bs, kt + 1, 1);
    __builtin_amdgcn_sched_barrier(0);
    __builtin_amdgcn_s_barrier();
    asm volatile("s_waitcnt lgkmcnt(0)" ::: "memory");
    __builtin_amdgcn_sched_barrier(0);
    __builtin_amdgcn_s_setprio(1);
#pragma unroll
    for (int f = 0; f < 4; ++f)
#pragma unroll
      for (int g = 0; g < 4; ++g)
        acc[4 + f][g] = __builtin_amdgcn_mfma_f32_16x16x32_f16(bf[g], af[f], acc[4 + f][g], 0, 0, 0);
    __builtin_amdgcn_s_setprio(0);
    if (kt == 11) asm volatile("s_waitcnt vmcnt(0)" ::: "memory");
    else          asm volatile("s_waitcnt vmcnt(8)" ::: "memory");
    __builtin_amdgcn_sched_barrier(0);
    __builtin_amdgcn_s_barrier();

    // ---------- P3 ----------
#pragma unroll
    for (int g = 0; g < 4; ++g)
      bf[g] = *(const half8*)(LB1 + (wc * 64 + g * 16 + frow) * 32 + ((fhi ^ fsw)) * 8);
#pragma unroll
    for (int f = 0; f < 4; ++f)
      af[f] = *(const half8*)(LA1 + (wr * 128 + f * 16 + frow) * 32 + ((fhi ^ fsw)) * 8);
    if (kt <= 9) STG(Abase, As, kt + 2, 0);
    __builtin_amdgcn_sched_barrier(0);
    __builtin_amdgcn_s_barrier();
    asm volatile("s_waitcnt lgkmcnt(0)" ::: "memory");
    __builtin_amdgcn_sched_barrier(0);
    __builtin_amdgcn_s_setprio(1);
#pragma unroll
    for (int f = 0; f < 4; ++f)
#pragma unroll
      for (int g = 0; g < 4; ++g)
        acc[f][g] = __builtin_amdgcn_mfma_f32_16x16x32_f16(bf[g], af[f], acc[f][g], 0, 0, 0);
    __builtin_amdgcn_s_setprio(0);
    __builtin_amdgcn_sched_barrier(0);
    __builtin_amdgcn_s_barrier();

    // ---------- P4 ----------
#pragma unroll
    for (int f = 0; f < 4; ++f)
      af[f] = *(const half8*)(LA1 + (wr * 128 + 64 + f * 16 + frow) * 32 + ((fhi ^ fsw)) * 8);
    if (kt <= 9) STG(Bbase, Bs, kt + 2, 0);
    __builtin_amdgcn_sched_barrier(0);
    __builtin_amdgcn_s_barrier();
    asm volatile("s_waitcnt lgkmcnt(0)" ::: "memory");
    __builtin_amdgcn_sched_barrier(0);
    __builtin_amdgcn_s_setprio(1);
#pragma unroll
    for (int f = 0; f < 4; ++f)
#pragma unroll
      for (int g = 0; g < 4; ++g)
        acc[4 + f][g] = __builtin_amdgcn_mfma_f32_16x16x32_f16(bf[g], af[f], acc[4 + f][g], 0, 0, 0);
    __builtin_amdgcn_s_setprio(0);
    if (kt == 7) {
#pragma unroll
      for (int i = 0; i < 8; ++i)
#pragma unroll
        for (int j = 0; j < 4; ++j)
#pragma unroll
          for (int r = 0; r < 4; ++r) acc[i][j][r] *= 0.000244140625f;
    }
    if (kt <= 9)       asm volatile("s_waitcnt vmcnt(8)" ::: "memory");
    else if (kt == 10) asm volatile("s_waitcnt vmcnt(4)" ::: "memory");
    __builtin_amdgcn_sched_barrier(0);
    __builtin_amdgcn_s_barrier();
  }
#undef STG

  // epilogue: swapped-operand C/D layout -> float4 stores (verified R9).
#pragma unroll
  for (int f = 0; f < 8; ++f) {
    int u = u0 + wr * 128 + f * 16 + frow;
    int a4 = u >> 6, ub = u & 63;
#pragma unroll
    for (int g = 0; g < 4; ++g) {
      int v = v0 + wc * 64 + g * 16 + fhi * 4;
      int c4 = v >> 6, vb = v & 63;
      float* p = X + ((size_t)(a4 * 64 + c4) << 12) + (ub << 6) + vb;
      *(float4*)p = (float4){acc[f][g][0], acc[f][g][1], acc[f][g][2], acc[f][g][3]};
    }
  }
}

// ---------------------------------------------------------------------------
// corr_diag: block = (diagonal d = qi-pi, chunk of up to 8 pi). Rolling
// 3-slot tile ring; per step stage ONE new tile, build Tsum, 3-tap stencil,
// partial argmax over pj written per (pi,qi) exactly once (layout unchanged).
__global__ __launch_bounds__(256) void corr_diag(const float* __restrict__ X,
                                                 float* __restrict__ pval,
                                                 int* __restrict__ pidx) {
  __shared__ float T[3][4096];
  __shared__ float Tsum[4096];
  __shared__ float mv[16][64];   // must follow Tsum (stencil overread, masked)
  __shared__ int mi[16][64];
  const int bx = blockIdx.x;                // 0..983
  const int di = bx >> 3, ch = bx & 7;
  const int d = di - 61;
  const int ad = d < 0 ? -d : d;
  const int p_lo = d < 0 ? -d : 0;
  const int L = 62 - ad;
  const int rem = L - ch * 8;
  if (rem <= 0) return;                     // block-uniform exit
  const int cnt = rem < 8 ? rem : 8;
  const int pi0 = p_lo + ch * 8, qi0 = pi0 + d;
  const int t = threadIdx.x;

  // prologue: stage tiles j=0,1 into ring slots 0,1
#pragma unroll
  for (int j = 0; j < 2; ++j) {
    const float* src = X + ((size_t)((pi0 + j) * 64 + (qi0 + j)) << 12);
#pragma unroll
    for (int k = 0; k < 4; ++k) {
      int e = k * 1024 + t * 4;
      *(float4*)&T[j][e] = *(const float4*)(src + e);
    }
  }

  for (int s = 0; s < cnt; ++s) {
    // stage tile j=s+2 into slot (s+2)%3
    {
      const float* src = X + ((size_t)((pi0 + s + 2) * 64 + (qi0 + s + 2)) << 12);
      float* dstT = T[(s + 2) % 3];
#pragma unroll
      for (int k = 0; k < 4; ++k) {
        int e = k * 1024 + t * 4;
        *(float4*)&dstT[e] = *(const float4*)(src + e);
      }
    }
    __syncthreads();   // staged tile visible; prev-step Tsum readers done

    // build Tsum = T[s%3] + T[(s+1)%3] + T[(s+2)%3]
    {
      const float* A0 = T[s % 3];
      const float* A1 = T[(s + 1) % 3];
      const float* A2 = T[(s + 2) % 3];
#pragma unroll
      for (int k = 0; k < 4; ++k) {
        int e = k * 1024 + t * 4;
        float4 a = *(const float4*)(A0 + e);
        float4 b = *(const float4*)(A1 + e);
        float4 c = *(const float4*)(A2 + e);
        *(float4*)&Tsum[e] = (float4){a.x + b.x + c.x, a.y + b.y + c.y,
                                      a.z + b.z + c.z, a.w + b.w + c.w};
      }
    }
    __syncthreads();

    // stencil + per-thread argmax (identical math/tie-break to prior corr)
    const int pg = t >> 4, qg = t & 15;
    const int pj0 = pg * 4, qj0 = qg * 4;
    float v[6][8];
#pragma unroll
    for (int r = 0; r < 6; ++r) {
      int rr = pj0 + r; if (rr > 63) rr = 63;
      *(float4*)&v[r][0] = *(const float4*)&Tsum[rr * 64 + qj0];
      *(float4*)&v[r][4] = *(const float4*)&Tsum[rr * 64 + qj0 + 4];
    }
    float acc[4][4];
#pragma unroll
    for (int i = 0; i < 4; ++i)
#pragma unroll
      for (int j = 0; j < 4; ++j)
        acc[i][j] = v[i][j] + v[i + 1][j + 1] + v[i + 2][j + 2];

    float bv[4]; int bp[4];
#pragma unroll
    for (int j = 0; j < 4; ++j) { bv[j] = -3.0e38f; bp[j] = 0; }
#pragma unroll
    for (int i = 0; i < 4; ++i) {
      bool pvalid = (pj0 + i) < 62;
#pragma unroll
      for (int j = 0; j < 4; ++j) {
        float val = pvalid ? acc[i][j] : -3.0e38f;
        if (val > bv[j]) { bv[j] = val; bp[j] = pj0 + i; }
      }
    }
#pragma unroll
    for (int j = 0; j < 4; ++j) { mv[pg][qj0 + j] = bv[j]; mi[pg][qj0 + j] = bp[j]; }
    __syncthreads();

    if (t < 62) {
      float best = -3.0e38f; int bpj = 0;
      for (int g = 0; g < 16; ++g) {         // ascending g = ascending pj
        float vv = mv[g][t];
        if (vv > best) { best = vv; bpj = mi[g][t]; }
      }
      const int pi = pi0 + s, qi = qi0 + s;
      int q = qi * 62 + t;
      pval[(size_t)pi * 3844 + q] = best;
      pidx[(size_t)pi * 3844 + q] = pi * 62 + bpj;
    }
  }
}

// ---------------------------------------------------------------------------
__global__ void argmax_reduce(const float* __restrict__ pval0, const int* __restrict__ pidx0,
                              const float* __restrict__ pval1, const int* __restrict__ pidx1,
                              int* __restrict__ fidx) {
  int qq2 = blockIdx.x * 256 + threadIdx.x;
  if (qq2 >= 7688) return;
  int b = qq2 >= 3844;
  int qq = qq2 - b * 3844;
  const float* pv = b ? pval1 : pval0;
  const int* px = b ? pidx1 : pidx0;
  float best = -3.0e38f;
  int bi = 0;
  for (int c = 0; c < 62; ++c) {
    float vv = pv[(size_t)c * 3844 + qq];
    if (vv > best) { best = vv; bi = px[(size_t)c * 3844 + qq]; }
  }
  fidx[qq2] = bi;
}

// ---------------------------------------------------------------------------
__global__ void flow_kernel(const int* __restrict__ fidx, float* __restrict__ out) {
  int t = blockIdx.x * 256 + threadIdx.x;
  if (t >= 147456) return;
  int comp = t & 1;
  int w = (t >> 1) & 63;
  int h = (t >> 7) & 63;
  int s = (t >> 13) % 9;
  int b = t / 73728;
  int i = s / 3, j = s % 3;
  int y = h - i, x = w - j;
  float val = 0.f;
  if (y >= 0 && x >= 0 && y < 62 && x < 62) {
    int idx = fidx[b * 3844 + y * 62 + x];
    val = (comp == 0) ? (float)(idx % 62) - (float)x : (float)(idx / 62) - (float)y;
  }
  out[t] = val;
}

// ---------------------------------------------------------------------------
extern "C" void kernel_launch(void* const* d_in, const int* in_sizes, int n_in,
                              void* d_out, int out_size, void* d_ws, size_t ws_size,
                              hipStream_t stream) {
  const float* df1 = (const float*)d_in[0];  // input  -> B operand (columns v)
  const float* df2 = (const float*)d_in[1];  // ref    -> A operand (rows u)
  float* out = (float*)d_out;

  char* ws = (char*)d_ws;
  _Float16* Apack = (_Float16*)ws;                       // 2*4096*768 f16
  _Float16* Bpack = (_Float16*)(ws + 12582912);
  float* X = (float*)(ws + 25165824);                    // 64 MiB tile-major
  float* pval0 = (float*)(ws + 25165824 + 67108864);     // 62*3844 f32
  int* pidx0 = (int*)((char*)pval0 + 953312);
  int* fidx = (int*)((char*)pidx0 + 953312);             // 7688 int
  float* pval1 = (float*)Apack;                          // dead after gemm(b=1)
  int* pidx1 = (int*)((char*)Apack + 953312);

  prep_kernel<<<256, 256, 0, stream>>>(df1, df2, Apack, Bpack);

  gemm_mfma<<<256, 512, 0, stream>>>(Apack, Bpack, X);
  corr_diag<<<984, 256, 0, stream>>>(X, pval0, pidx0);
  gemm_mfma<<<256, 512, 0, stream>>>(Apack + 3145728, Bpack + 3145728, X);
  corr_diag<<<984, 256, 0, stream>>>(X, pval1, pidx1);

  argmax_reduce<<<32, 256, 0, stream>>>(pval0, pidx0, pval1, pidx1, fidx);
  flow_kernel<<<576, 256, 0, stream>>>(fidx, out);
}

// Round 11
// 182.694 us; speedup vs baseline: 1.1259x; 1.1259x over previous
//
#include <hip/hip_runtime.h>

// B=2, C=256, H=W=64, P=3 -> Hp=Wp=62, Np=3844.
// X = A^T B via f16 MFMA hi/lo split (K=768), stored TILE-MAJOR.
// GEMM: 256x256 tile, BK=64, 8 waves (2x4), TWO phases per K-tile (32 MFMA
// per barrier pair), counted vmcnt(8) ledger, swapped-operand MFMA ->
// float4 epilogue. corr: R7's separable Tsum kernel (3844 indep blocks).

typedef _Float16 half8 __attribute__((ext_vector_type(8)));
typedef float floatx4 __attribute__((ext_vector_type(4)));
typedef __attribute__((address_space(1))) const void gv_t;
typedef __attribute__((address_space(3))) void lv_t;

// ---------------------------------------------------------------------------
// prep: per-pixel L2 norm + f16 hi/lo split + pack [pix][768] with 4-slot XOR
// pre-swizzle. 4 threads per pixel (c-quarters).
__global__ void prep_kernel(const float* __restrict__ df1, const float* __restrict__ df2,
                            _Float16* __restrict__ Apack, _Float16* __restrict__ Bpack) {
  __shared__ float red[256];
  const int tid = threadIdx.x, q = tid >> 6, lane = tid & 63;
  int g = blockIdx.x * 64 + lane;           // pixel-task 0..16383
  int pix = g & 4095;
  int bm = g >> 12;
  int b = bm >> 1, m = bm & 1;              // m=0: df1 -> Bpack, m=1: df2 -> Apack
  const float* src = (m ? df2 : df1) + (size_t)b * 1048576 + pix;

  float ss = 0.f;
  for (int c = q * 64; c < q * 64 + 64; ++c) {
    float v = src[(size_t)c * 4096];
    ss += v * v;
  }
  red[tid] = ss;
  __syncthreads();
  float tot = red[lane] + red[lane + 64] + red[lane + 128] + red[lane + 192];
  float sc = 1.f / fmaxf(sqrtf(tot), 1e-12f);

  _Float16* dst = (m ? Apack : Bpack) + (size_t)b * 3145728 + (size_t)pix * 768;
  const int swz = (pix >> 1) & 3;

  for (int c0 = q * 64; c0 < q * 64 + 64; c0 += 8) {
    half8 hi, lo;
#pragma unroll
    for (int j = 0; j < 8; ++j) {
      float v = src[(size_t)(c0 + j) * 4096] * sc;
      _Float16 h = (_Float16)v;
      hi[j] = h;
      lo[j] = (_Float16)(4096.f * (v - (float)h));
    }
    int o = (c0 >> 3) & 31;
    int oS = (o & ~3) | ((o & 3) ^ swz);
    if (m) {  // A = [hi | lo | hi]
      *(half8*)(dst + oS * 8) = hi;
      *(half8*)(dst + 256 + oS * 8) = lo;
      *(half8*)(dst + 512 + oS * 8) = hi;
    } else {  // B = [lo | hi | hi]
      *(half8*)(dst + oS * 8) = lo;
      *(half8*)(dst + 256 + oS * 8) = hi;
      *(half8*)(dst + 512 + oS * 8) = hi;
    }
  }
}

// ---------------------------------------------------------------------------
__global__ __launch_bounds__(512, 2) void gemm_mfma(const _Float16* __restrict__ A,
                                                    const _Float16* __restrict__ B,
                                                    float* __restrict__ X) {
  __shared__ _Float16 As[2][2][256][32];    // [buf][khalf][row][32 f16] = 64 KB
  __shared__ _Float16 Bs[2][2][256][32];    // 64 KB

  int bid = blockIdx.x & 255;               // XCD swizzle (256 blocks, 256%8==0)
  int swb = (bid & 7) * 32 + (bid >> 3);
  int bx = swb & 15, by = swb >> 4;
  const int u0 = by << 8, v0 = bx << 8;

  const int tid = threadIdx.x, lane = tid & 63, wid = tid >> 6;
  const int wr = wid >> 2, wc = wid & 3;    // 2 x 4 waves; per-wave out 128x64
  const int frow = lane & 15, fhi = lane >> 4;
  const int fsw = (lane >> 1) & 3;
  const int fslot = (fhi ^ fsw) * 8;

  floatx4 acc[8][4];
#pragma unroll
  for (int i = 0; i < 8; ++i)
#pragma unroll
    for (int j = 0; j < 4; ++j) acc[i][j] = (floatx4){0.f, 0.f, 0.f, 0.f};

  const _Float16* Abase = A + (size_t)u0 * 768;
  const _Float16* Bbase = B + (size_t)v0 * 768;

#define STG(OPB, LDSB, kt, kh)                                                \
  {                                                                           \
    _Pragma("unroll") for (int i_ = 0; i_ < 2; ++i_) {                        \
      int c_ = i_ * 512 + tid;                                                \
      int r_ = c_ >> 2, s_ = c_ & 3;                                          \
      __builtin_amdgcn_global_load_lds(                                       \
          (gv_t*)(OPB + (size_t)r_ * 768 + (kt) * 64 + (kh) * 32 + s_ * 8),   \
          (lv_t*)(&LDSB[(kt) & 1][kh][0][0] + c_ * 8), 16, 0, 0);             \
    }                                                                         \
  }

  // prologue: kh0(0), kh1(0), kh0(1) staged = 12 loads/thread-group
  STG(Abase, As, 0, 0); STG(Bbase, Bs, 0, 0);
  STG(Abase, As, 0, 1); STG(Bbase, Bs, 0, 1);
  STG(Abase, As, 1, 0); STG(Bbase, Bs, 1, 0);
  asm volatile("s_waitcnt vmcnt(8)" ::: "memory");    // kh0(0) A,B landed
  __builtin_amdgcn_sched_barrier(0);
  __builtin_amdgcn_s_barrier();

  for (int kt = 0; kt < 12; ++kt) {
    const int buf = kt & 1;
    const _Float16* LA0 = &As[buf][0][0][0];
    const _Float16* LB0 = &Bs[buf][0][0][0];
    const _Float16* LA1 = &As[buf][1][0][0];
    const _Float16* LB1 = &Bs[buf][1][0][0];
    half8 bf[4], af0[4], af1[4];

    // ========== Phase A: kh0 -> 32 MFMA ==========
#pragma unroll
    for (int g = 0; g < 4; ++g)
      bf[g] = *(const half8*)(LB0 + (wc * 64 + g * 16 + frow) * 32 + fslot);
#pragma unroll
    for (int f = 0; f < 4; ++f)
      af0[f] = *(const half8*)(LA0 + (wr * 128 + f * 16 + frow) * 32 + fslot);
#pragma unroll
    for (int f = 0; f < 4; ++f)
      af1[f] = *(const half8*)(LA0 + (wr * 128 + 64 + f * 16 + frow) * 32 + fslot);
    if (kt <= 10) { STG(Abase, As, kt + 1, 1); STG(Bbase, Bs, kt + 1, 1); }
    __builtin_amdgcn_sched_barrier(0);
    __builtin_amdgcn_s_barrier();
    asm volatile("s_waitcnt lgkmcnt(0)" ::: "memory");
    __builtin_amdgcn_sched_barrier(0);
    __builtin_amdgcn_s_setprio(1);
#pragma unroll
    for (int f = 0; f < 4; ++f)
#pragma unroll
      for (int g = 0; g < 4; ++g)
        acc[f][g] = __builtin_amdgcn_mfma_f32_16x16x32_f16(bf[g], af0[f], acc[f][g], 0, 0, 0);
#pragma unroll
    for (int f = 0; f < 4; ++f)
#pragma unroll
      for (int g = 0; g < 4; ++g)
        acc[4 + f][g] = __builtin_amdgcn_mfma_f32_16x16x32_f16(bf[g], af1[f], acc[4 + f][g], 0, 0, 0);
    __builtin_amdgcn_s_setprio(0);
    __builtin_amdgcn_sched_barrier(0);
    if (kt <= 10) asm volatile("s_waitcnt vmcnt(8)" ::: "memory");  // kh1(kt) landed
    else          asm volatile("s_waitcnt vmcnt(0)" ::: "memory");
    __builtin_amdgcn_sched_barrier(0);
    __builtin_amdgcn_s_barrier();

    // ========== Phase B: kh1 -> 32 MFMA ==========
#pragma unroll
    for (int g = 0; g < 4; ++g)
      bf[g] = *(const half8*)(LB1 + (wc * 64 + g * 16 + frow) * 32 + fslot);
#pragma unroll
    for (int f = 0; f < 4; ++f)
      af0[f] = *(const half8*)(LA1 + (wr * 128 + f * 16 + frow) * 32 + fslot);
#pragma unroll
    for (int f = 0; f < 4; ++f)
      af1[f] = *(const half8*)(LA1 + (wr * 128 + 64 + f * 16 + frow) * 32 + fslot);
    if (kt <= 9) { STG(Abase, As, kt + 2, 0); STG(Bbase, Bs, kt + 2, 0); }
    __builtin_amdgcn_sched_barrier(0);
    __builtin_amdgcn_s_barrier();
    asm volatile("s_waitcnt lgkmcnt(0)" ::: "memory");
    __builtin_amdgcn_sched_barrier(0);
    __builtin_amdgcn_s_setprio(1);
#pragma unroll
    for (int f = 0; f < 4; ++f)
#pragma unroll
      for (int g = 0; g < 4; ++g)
        acc[f][g] = __builtin_amdgcn_mfma_f32_16x16x32_f16(bf[g], af0[f], acc[f][g], 0, 0, 0);
#pragma unroll
    for (int f = 0; f < 4; ++f)
#pragma unroll
      for (int g = 0; g < 4; ++g)
        acc[4 + f][g] = __builtin_amdgcn_mfma_f32_16x16x32_f16(bf[g], af1[f], acc[4 + f][g], 0, 0, 0);
    __builtin_amdgcn_s_setprio(0);
    __builtin_amdgcn_sched_barrier(0);
    if (kt == 7) {  // cross terms (K<512) done -> scale by 2^-12 before hi*hi
#pragma unroll
      for (int i = 0; i < 8; ++i)
#pragma unroll
        for (int j = 0; j < 4; ++j)
#pragma unroll
          for (int r = 0; r < 4; ++r) acc[i][j][r] *= 0.000244140625f;
    }
    if (kt <= 9)       asm volatile("s_waitcnt vmcnt(8)" ::: "memory");  // kh0(kt+1)
    else if (kt == 10) asm volatile("s_waitcnt vmcnt(4)" ::: "memory");
    __builtin_amdgcn_sched_barrier(0);
    __builtin_amdgcn_s_barrier();
  }
#undef STG

  // epilogue: swapped-operand C/D layout -> float4 stores (verified R9/R10).
#pragma unroll
  for (int f = 0; f < 8; ++f) {
    int u = u0 + wr * 128 + f * 16 + frow;
    int a4 = u >> 6, ub = u & 63;
#pragma unroll
    for (int g = 0; g < 4; ++g) {
      int v = v0 + wc * 64 + g * 16 + fhi * 4;
      int c4 = v >> 6, vb = v & 63;
      float* p = X + ((size_t)(a4 * 64 + c4) << 12) + (ub << 6) + vb;
      *(float4*)p = (float4){acc[f][g][0], acc[f][g][1], acc[f][g][2], acc[f][g][3]};
    }
  }
}

// ---------------------------------------------------------------------------
// corr_argmax (R7, proven): block (qi,pi). Tsum = sum_di tile(pi+di,qi+di)
// via register staging, then corr[pj][qj] = sum_dj Tsum[pj+dj][qj+dj];
// partial argmax over pj (first-max, ascending).
__global__ __launch_bounds__(256) void corr_argmax(const float* __restrict__ X,
                                                   float* __restrict__ pval,
                                                   int* __restrict__ pidx) {
  __shared__ float Tsum[4096];
  __shared__ float mv[16][64];   // must follow Tsum (stencil overread, masked)
  __shared__ int mi[16][64];
  const int qi = blockIdx.x, pi = blockIdx.y;
  const int t = threadIdx.x;

  const float* t0 = X + ((size_t)((pi + 0) * 64 + (qi + 0)) << 12);
  const float* t1 = X + ((size_t)((pi + 1) * 64 + (qi + 1)) << 12);
  const float* t2 = X + ((size_t)((pi + 2) * 64 + (qi + 2)) << 12);
#pragma unroll
  for (int k = 0; k < 4; ++k) {
    int e = k * 1024 + t * 4;
    float4 a = *(const float4*)(t0 + e);
    float4 b = *(const float4*)(t1 + e);
    float4 c = *(const float4*)(t2 + e);
    *(float4*)&Tsum[e] = (float4){a.x + b.x + c.x, a.y + b.y + c.y,
                                  a.z + b.z + c.z, a.w + b.w + c.w};
  }
  __syncthreads();

  const int pg = t >> 4, qg = t & 15;
  const int pj0 = pg * 4, qj0 = qg * 4;

  float v[6][8];
#pragma unroll
  for (int r = 0; r < 6; ++r) {
    int rr = pj0 + r; if (rr > 63) rr = 63;   // clamped rows feed only invalid pj
    *(float4*)&v[r][0] = *(const float4*)&Tsum[rr * 64 + qj0];
    *(float4*)&v[r][4] = *(const float4*)&Tsum[rr * 64 + qj0 + 4];
  }

  float acc[4][4];
#pragma unroll
  for (int i = 0; i < 4; ++i)
#pragma unroll
    for (int j = 0; j < 4; ++j)
      acc[i][j] = v[i][j] + v[i + 1][j + 1] + v[i + 2][j + 2];

  float bv[4]; int bp[4];
#pragma unroll
  for (int j = 0; j < 4; ++j) { bv[j] = -3.0e38f; bp[j] = 0; }
#pragma unroll
  for (int i = 0; i < 4; ++i) {
    bool pvalid = (pj0 + i) < 62;
#pragma unroll
    for (int j = 0; j < 4; ++j) {
      float val = pvalid ? acc[i][j] : -3.0e38f;
      if (val > bv[j]) { bv[j] = val; bp[j] = pj0 + i; }
    }
  }
#pragma unroll
  for (int j = 0; j < 4; ++j) { mv[pg][qj0 + j] = bv[j]; mi[pg][qj0 + j] = bp[j]; }
  __syncthreads();

  if (t < 62) {
    float best = -3.0e38f; int bpj = 0;
    for (int g = 0; g < 16; ++g) {           // ascending g = ascending pj
      float vv = mv[g][t];
      if (vv > best) { best = vv; bpj = mi[g][t]; }
    }
    int q = qi * 62 + t;
    pval[(size_t)pi * 3844 + q] = best;
    pidx[(size_t)pi * 3844 + q] = pi * 62 + bpj;
  }
}

// ---------------------------------------------------------------------------
__global__ void argmax_reduce(const float* __restrict__ pval0, const int* __restrict__ pidx0,
                              const float* __restrict__ pval1, const int* __restrict__ pidx1,
                              int* __restrict__ fidx) {
  int qq2 = blockIdx.x * 256 + threadIdx.x;
  if (qq2 >= 7688) return;
  int b = qq2 >= 3844;
  int qq = qq2 - b * 3844;
  const float* pv = b ? pval1 : pval0;
  const int* px = b ? pidx1 : pidx0;
  float best = -3.0e38f;
  int bi = 0;
  for (int c = 0; c < 62; ++c) {
    float vv = pv[(size_t)c * 3844 + qq];
    if (vv > best) { best = vv; bi = px[(size_t)c * 3844 + qq]; }
  }
  fidx[qq2] = bi;
}

// ---------------------------------------------------------------------------
__global__ void flow_kernel(const int* __restrict__ fidx, float* __restrict__ out) {
  int t = blockIdx.x * 256 + threadIdx.x;
  if (t >= 147456) return;
  int comp = t & 1;
  int w = (t >> 1) & 63;
  int h = (t >> 7) & 63;
  int s = (t >> 13) % 9;
  int b = t / 73728;
  int i = s / 3, j = s % 3;
  int y = h - i, x = w - j;
  float val = 0.f;
  if (y >= 0 && x >= 0 && y < 62 && x < 62) {
    int idx = fidx[b * 3844 + y * 62 + x];
    val = (comp == 0) ? (float)(idx % 62) - (float)x : (float)(idx / 62) - (float)y;
  }
  out[t] = val;
}

// ---------------------------------------------------------------------------
extern "C" void kernel_launch(void* const* d_in, const int* in_sizes, int n_in,
                              void* d_out, int out_size, void* d_ws, size_t ws_size,
                              hipStream_t stream) {
  const float* df1 = (const float*)d_in[0];  // input  -> B operand (columns v)
  const float* df2 = (const float*)d_in[1];  // ref    -> A operand (rows u)
  float* out = (float*)d_out;

  char* ws = (char*)d_ws;
  _Float16* Apack = (_Float16*)ws;                       // 2*4096*768 f16
  _Float16* Bpack = (_Float16*)(ws + 12582912);
  float* X = (float*)(ws + 25165824);                    // 64 MiB tile-major
  float* pval0 = (float*)(ws + 25165824 + 67108864);     // 62*3844 f32
  int* pidx0 = (int*)((char*)pval0 + 953312);
  int* fidx = (int*)((char*)pidx0 + 953312);             // 7688 int
  float* pval1 = (float*)Apack;                          // batch-0 pack region,
  int* pidx1 = (int*)((char*)Apack + 953312);            // dead after gemm(b=0)

  prep_kernel<<<256, 256, 0, stream>>>(df1, df2, Apack, Bpack);

  gemm_mfma<<<256, 512, 0, stream>>>(Apack, Bpack, X);
  corr_argmax<<<dim3(62, 62), 256, 0, stream>>>(X, pval0, pidx0);
  gemm_mfma<<<256, 512, 0, stream>>>(Apack + 3145728, Bpack + 3145728, X);
  corr_argmax<<<dim3(62, 62), 256, 0, stream>>>(X, pval1, pidx1);

  argmax_reduce<<<32, 256, 0, stream>>>(pval0, pidx0, pval1, pidx1, fidx);
  flow_kernel<<<576, 256, 0, stream>>>(fidx, out);
}

// Round 12
// 161.392 us; speedup vs baseline: 1.2745x; 1.1320x over previous
//
#include <hip/hip_runtime.h>

// B=2, C=256, H=W=64, P=3 -> Hp=Wp=62, Np=3844.
// X = A^T B via f16 MFMA hi/lo split (K=768), stored TILE-MAJOR.
// Pack layout is K-MAJOR: P[octet o][pix][8 f16], o = seg*32 + (c>>3),
// segments: A=[hi|lo|hi], B=[lo|hi|hi]. prep writes PLAIN (coalesced 1KB/wave);
// the GEMM applies the XOR swizzle in the per-lane GLOBAL source address of
// global_load_lds (LDS dest linear), giving LDS[row][s] = octet (s^((row>>1)&3))
// -- identical LDS contents to rounds 7-11 (verified algebraically).
// GEMM: 256x256 tile, BK=64, 8 waves, 2 phases/kt (R11, proven 43.5us),
// dual-batch 512-block dispatch (R9-proven -8us). corr: R7/R9 separable Tsum.

typedef _Float16 half8 __attribute__((ext_vector_type(8)));
typedef float floatx4 __attribute__((ext_vector_type(4)));
typedef __attribute__((address_space(1))) const void gv_t;
typedef __attribute__((address_space(3))) void lv_t;

// ---------------------------------------------------------------------------
// prep: SINGLE-PASS per-pixel L2 norm + f16 hi/lo split + k-major pack.
// 4 threads/pixel; each holds its 64 channels in registers (static indexing).
__global__ void prep_kernel(const float* __restrict__ df1, const float* __restrict__ df2,
                            _Float16* __restrict__ Apack, _Float16* __restrict__ Bpack) {
  __shared__ float red[256];
  const int tid = threadIdx.x, q = tid >> 6, lane = tid & 63;
  int g = blockIdx.x * 64 + lane;           // pixel-task 0..16383
  int pix = g & 4095;
  int bm = g >> 12;
  int b = bm >> 1, m = bm & 1;              // m=0: df1 -> Bpack, m=1: df2 -> Apack
  const float* src = (m ? df2 : df1) + (size_t)b * 1048576 + pix;

  float v[64];
#pragma unroll
  for (int j = 0; j < 64; ++j) v[j] = src[(size_t)(q * 64 + j) * 4096];

  float ss = 0.f;
#pragma unroll
  for (int j = 0; j < 64; ++j) ss += v[j] * v[j];
  red[tid] = ss;
  __syncthreads();
  float tot = red[lane] + red[lane + 64] + red[lane + 128] + red[lane + 192];
  float sc = 1.f / fmaxf(sqrtf(tot), 1e-12f);

  _Float16* P = (m ? Apack : Bpack) + (size_t)b * 3145728;

#pragma unroll
  for (int j0 = 0; j0 < 64; j0 += 8) {
    half8 hi, lo;
#pragma unroll
    for (int j = 0; j < 8; ++j) {
      float x = v[j0 + j] * sc;
      _Float16 h = (_Float16)x;
      hi[j] = h;
      lo[j] = (_Float16)(4096.f * (x - (float)h));
    }
    int oj = q * 8 + (j0 >> 3);             // octet-in-segment 0..31
    _Float16* p0 = P + ((size_t)oj * 4096 + pix) * 8;          // seg 0
    _Float16* p1 = P + ((size_t)(32 + oj) * 4096 + pix) * 8;   // seg 1
    _Float16* p2 = P + ((size_t)(64 + oj) * 4096 + pix) * 8;   // seg 2
    if (m) { *(half8*)p0 = hi; *(half8*)p1 = lo; *(half8*)p2 = hi; }   // A=[hi|lo|hi]
    else   { *(half8*)p0 = lo; *(half8*)p1 = hi; *(half8*)p2 = hi; }   // B=[lo|hi|hi]
  }
}

// ---------------------------------------------------------------------------
// Dual-batch GEMM: blocks [0,256) -> batch 0, [256,512) -> batch 1.
__global__ __launch_bounds__(512, 2) void gemm_mfma(const _Float16* __restrict__ A,
                                                    const _Float16* __restrict__ B,
                                                    float* __restrict__ X) {
  __shared__ _Float16 As[2][2][256][32];    // [buf][khalf][row][32 f16] = 64 KB
  __shared__ _Float16 Bs[2][2][256][32];    // 64 KB

  const int batch = blockIdx.x >> 8;
  int bid = blockIdx.x & 255;               // XCD swizzle within each batch
  int swb = (bid & 7) * 32 + (bid >> 3);
  int bx = swb & 15, by = swb >> 4;
  const int u0 = by << 8, v0 = bx << 8;

  const int tid = threadIdx.x, lane = tid & 63, wid = tid >> 6;
  const int wr = wid >> 2, wc = wid & 3;    // 2 x 4 waves; per-wave out 128x64
  const int frow = lane & 15, fhi = lane >> 4;
  const int fsw = (lane >> 1) & 3;
  const int fslot = (fhi ^ fsw) * 8;

  floatx4 acc[8][4];
#pragma unroll
  for (int i = 0; i < 8; ++i)
#pragma unroll
    for (int j = 0; j < 4; ++j) acc[i][j] = (floatx4){0.f, 0.f, 0.f, 0.f};

  // k-major pack: element addr = (o*4096 + pixel)*8 ; pixel = u0|v0 + row
  const _Float16* Abase = A + (size_t)batch * 3145728 + (size_t)u0 * 8;
  const _Float16* Bbase = B + (size_t)batch * 3145728 + (size_t)v0 * 8;
  float* Xb = X + (size_t)batch * 16777216;

  // STG: LDS[buf][kh][row][s] <- global octet (kt*8 + kh*4 + (s ^ ((row>>1)&3)))
  // of pixel row. LDS dest linear; swizzle lives in the per-lane source addr.
#define STG(OPB, LDSB, kt, kh)                                                \
  {                                                                           \
    _Pragma("unroll") for (int i_ = 0; i_ < 2; ++i_) {                        \
      int c_ = i_ * 512 + tid;                                                \
      int r_ = c_ >> 2, s_ = c_ & 3;                                          \
      int o_ = (kt) * 8 + (kh) * 4 + (s_ ^ ((r_ >> 1) & 3));                  \
      __builtin_amdgcn_global_load_lds(                                       \
          (gv_t*)(OPB + ((size_t)o_ * 4096 + r_) * 8),                        \
          (lv_t*)(&LDSB[(kt) & 1][kh][0][0] + c_ * 8), 16, 0, 0);             \
    }                                                                         \
  }

  // prologue: kh0(0), kh1(0), kh0(1) staged
  STG(Abase, As, 0, 0); STG(Bbase, Bs, 0, 0);
  STG(Abase, As, 0, 1); STG(Bbase, Bs, 0, 1);
  STG(Abase, As, 1, 0); STG(Bbase, Bs, 1, 0);
  asm volatile("s_waitcnt vmcnt(8)" ::: "memory");    // kh0(0) A,B landed
  __builtin_amdgcn_sched_barrier(0);
  __builtin_amdgcn_s_barrier();

  for (int kt = 0; kt < 12; ++kt) {
    const int buf = kt & 1;
    const _Float16* LA0 = &As[buf][0][0][0];
    const _Float16* LB0 = &Bs[buf][0][0][0];
    const _Float16* LA1 = &As[buf][1][0][0];
    const _Float16* LB1 = &Bs[buf][1][0][0];
    half8 bf[4], af0[4], af1[4];

    // ========== Phase A: kh0 -> 32 MFMA ==========
#pragma unroll
    for (int g = 0; g < 4; ++g)
      bf[g] = *(const half8*)(LB0 + (wc * 64 + g * 16 + frow) * 32 + fslot);
#pragma unroll
    for (int f = 0; f < 4; ++f)
      af0[f] = *(const half8*)(LA0 + (wr * 128 + f * 16 + frow) * 32 + fslot);
#pragma unroll
    for (int f = 0; f < 4; ++f)
      af1[f] = *(const half8*)(LA0 + (wr * 128 + 64 + f * 16 + frow) * 32 + fslot);
    if (kt <= 10) { STG(Abase, As, kt + 1, 1); STG(Bbase, Bs, kt + 1, 1); }
    __builtin_amdgcn_sched_barrier(0);
    __builtin_amdgcn_s_barrier();
    asm volatile("s_waitcnt lgkmcnt(0)" ::: "memory");
    __builtin_amdgcn_sched_barrier(0);
    __builtin_amdgcn_s_setprio(1);
#pragma unroll
    for (int f = 0; f < 4; ++f)
#pragma unroll
      for (int g = 0; g < 4; ++g)
        acc[f][g] = __builtin_amdgcn_mfma_f32_16x16x32_f16(bf[g], af0[f], acc[f][g], 0, 0, 0);
#pragma unroll
    for (int f = 0; f < 4; ++f)
#pragma unroll
      for (int g = 0; g < 4; ++g)
        acc[4 + f][g] = __builtin_amdgcn_mfma_f32_16x16x32_f16(bf[g], af1[f], acc[4 + f][g], 0, 0, 0);
    __builtin_amdgcn_s_setprio(0);
    __builtin_amdgcn_sched_barrier(0);
    if (kt <= 10) asm volatile("s_waitcnt vmcnt(8)" ::: "memory");  // kh1(kt) landed
    else          asm volatile("s_waitcnt vmcnt(0)" ::: "memory");
    __builtin_amdgcn_sched_barrier(0);
    __builtin_amdgcn_s_barrier();

    // ========== Phase B: kh1 -> 32 MFMA ==========
#pragma unroll
    for (int g = 0; g < 4; ++g)
      bf[g] = *(const half8*)(LB1 + (wc * 64 + g * 16 + frow) * 32 + fslot);
#pragma unroll
    for (int f = 0; f < 4; ++f)
      af0[f] = *(const half8*)(LA1 + (wr * 128 + f * 16 + frow) * 32 + fslot);
#pragma unroll
    for (int f = 0; f < 4; ++f)
      af1[f] = *(const half8*)(LA1 + (wr * 128 + 64 + f * 16 + frow) * 32 + fslot);
    if (kt <= 9) { STG(Abase, As, kt + 2, 0); STG(Bbase, Bs, kt + 2, 0); }
    __builtin_amdgcn_sched_barrier(0);
    __builtin_amdgcn_s_barrier();
    asm volatile("s_waitcnt lgkmcnt(0)" ::: "memory");
    __builtin_amdgcn_sched_barrier(0);
    __builtin_amdgcn_s_setprio(1);
#pragma unroll
    for (int f = 0; f < 4; ++f)
#pragma unroll
      for (int g = 0; g < 4; ++g)
        acc[f][g] = __builtin_amdgcn_mfma_f32_16x16x32_f16(bf[g], af0[f], acc[f][g], 0, 0, 0);
#pragma unroll
    for (int f = 0; f < 4; ++f)
#pragma unroll
      for (int g = 0; g < 4; ++g)
        acc[4 + f][g] = __builtin_amdgcn_mfma_f32_16x16x32_f16(bf[g], af1[f], acc[4 + f][g], 0, 0, 0);
    __builtin_amdgcn_s_setprio(0);
    __builtin_amdgcn_sched_barrier(0);
    if (kt == 7) {  // cross terms (K<512) done -> scale by 2^-12 before hi*hi
#pragma unroll
      for (int i = 0; i < 8; ++i)
#pragma unroll
        for (int j = 0; j < 4; ++j)
#pragma unroll
          for (int r = 0; r < 4; ++r) acc[i][j][r] *= 0.000244140625f;
    }
    if (kt <= 9)       asm volatile("s_waitcnt vmcnt(8)" ::: "memory");  // kh0(kt+1)
    else if (kt == 10) asm volatile("s_waitcnt vmcnt(4)" ::: "memory");
    __builtin_amdgcn_sched_barrier(0);
    __builtin_amdgcn_s_barrier();
  }
#undef STG

  // epilogue: swapped-operand C/D layout -> float4 stores (verified R9-R11).
#pragma unroll
  for (int f = 0; f < 8; ++f) {
    int u = u0 + wr * 128 + f * 16 + frow;
    int a4 = u >> 6, ub = u & 63;
#pragma unroll
    for (int g = 0; g < 4; ++g) {
      int v = v0 + wc * 64 + g * 16 + fhi * 4;
      int c4 = v >> 6, vb = v & 63;
      float* p = Xb + ((size_t)(a4 * 64 + c4) << 12) + (ub << 6) + vb;
      *(float4*)p = (float4){acc[f][g][0], acc[f][g][1], acc[f][g][2], acc[f][g][3]};
    }
  }
}

// ---------------------------------------------------------------------------
// corr_argmax: block (qi,pi,z). Tsum = sum_di tile(pi+di,qi+di) via register
// staging, then corr[pj][qj] = sum_dj Tsum[pj+dj][qj+dj]; partial argmax over
// pj (first-max, ascending). z = batch.
__global__ __launch_bounds__(256) void corr_argmax(const float* __restrict__ X,
                                                   float* __restrict__ pval,
                                                   int* __restrict__ pidx,
                                                   long xstride) {
  __shared__ float Tsum[4096];
  __shared__ float mv[16][64];   // must follow Tsum (stencil overread, masked)
  __shared__ int mi[16][64];
  const int qi = blockIdx.x, pi = blockIdx.y, z = blockIdx.z;
  const int t = threadIdx.x;
  const float* Xz = X + (size_t)z * xstride;
  float* pvz = pval + (size_t)z * 238328;
  int* piz = pidx + (size_t)z * 238328;

  const float* t0 = Xz + ((size_t)((pi + 0) * 64 + (qi + 0)) << 12);
  const float* t1 = Xz + ((size_t)((pi + 1) * 64 + (qi + 1)) << 12);
  const float* t2 = Xz + ((size_t)((pi + 2) * 64 + (qi + 2)) << 12);
#pragma unroll
  for (int k = 0; k < 4; ++k) {
    int e = k * 1024 + t * 4;
    float4 a = *(const float4*)(t0 + e);
    float4 b = *(const float4*)(t1 + e);
    float4 c = *(const float4*)(t2 + e);
    *(float4*)&Tsum[e] = (float4){a.x + b.x + c.x, a.y + b.y + c.y,
                                  a.z + b.z + c.z, a.w + b.w + c.w};
  }
  __syncthreads();

  const int pg = t >> 4, qg = t & 15;
  const int pj0 = pg * 4, qj0 = qg * 4;

  float v[6][8];
#pragma unroll
  for (int r = 0; r < 6; ++r) {
    int rr = pj0 + r; if (rr > 63) rr = 63;   // clamped rows feed only invalid pj
    *(float4*)&v[r][0] = *(const float4*)&Tsum[rr * 64 + qj0];
    *(float4*)&v[r][4] = *(const float4*)&Tsum[rr * 64 + qj0 + 4];
  }

  float acc[4][4];
#pragma unroll
  for (int i = 0; i < 4; ++i)
#pragma unroll
    for (int j = 0; j < 4; ++j)
      acc[i][j] = v[i][j] + v[i + 1][j + 1] + v[i + 2][j + 2];

  float bv[4]; int bp[4];
#pragma unroll
  for (int j = 0; j < 4; ++j) { bv[j] = -3.0e38f; bp[j] = 0; }
#pragma unroll
  for (int i = 0; i < 4; ++i) {
    bool pvalid = (pj0 + i) < 62;
#pragma unroll
    for (int j = 0; j < 4; ++j) {
      float val = pvalid ? acc[i][j] : -3.0e38f;
      if (val > bv[j]) { bv[j] = val; bp[j] = pj0 + i; }
    }
  }
#pragma unroll
  for (int j = 0; j < 4; ++j) { mv[pg][qj0 + j] = bv[j]; mi[pg][qj0 + j] = bp[j]; }
  __syncthreads();

  if (t < 62) {
    float best = -3.0e38f; int bpj = 0;
    for (int g = 0; g < 16; ++g) {           // ascending g = ascending pj
      float vv = mv[g][t];
      if (vv > best) { best = vv; bpj = mi[g][t]; }
    }
    int q = qi * 62 + t;
    pvz[(size_t)pi * 3844 + q] = best;
    piz[(size_t)pi * 3844 + q] = pi * 62 + bpj;
  }
}

// ---------------------------------------------------------------------------
__global__ void argmax_reduce(const float* __restrict__ pval0, const int* __restrict__ pidx0,
                              const float* __restrict__ pval1, const int* __restrict__ pidx1,
                              int* __restrict__ fidx) {
  int qq2 = blockIdx.x * 256 + threadIdx.x;
  if (qq2 >= 7688) return;
  int b = qq2 >= 3844;
  int qq = qq2 - b * 3844;
  const float* pv = b ? pval1 : pval0;
  const int* px = b ? pidx1 : pidx0;
  float best = -3.0e38f;
  int bi = 0;
  for (int c = 0; c < 62; ++c) {
    float vv = pv[(size_t)c * 3844 + qq];
    if (vv > best) { best = vv; bi = px[(size_t)c * 3844 + qq]; }
  }
  fidx[qq2] = bi;
}

// ---------------------------------------------------------------------------
__global__ void flow_kernel(const int* __restrict__ fidx, float* __restrict__ out) {
  int t = blockIdx.x * 256 + threadIdx.x;
  if (t >= 147456) return;
  int comp = t & 1;
  int w = (t >> 1) & 63;
  int h = (t >> 7) & 63;
  int s = (t >> 13) % 9;
  int b = t / 73728;
  int i = s / 3, j = s % 3;
  int y = h - i, x = w - j;
  float val = 0.f;
  if (y >= 0 && x >= 0 && y < 62 && x < 62) {
    int idx = fidx[b * 3844 + y * 62 + x];
    val = (comp == 0) ? (float)(idx % 62) - (float)x : (float)(idx / 62) - (float)y;
  }
  out[t] = val;
}

// ---------------------------------------------------------------------------
extern "C" void kernel_launch(void* const* d_in, const int* in_sizes, int n_in,
                              void* d_out, int out_size, void* d_ws, size_t ws_size,
                              hipStream_t stream) {
  const float* df1 = (const float*)d_in[0];  // input  -> B operand (columns v)
  const float* df2 = (const float*)d_in[1];  // ref    -> A operand (rows u)
  float* out = (float*)d_out;

  char* ws = (char*)d_ws;
  _Float16* Apack = (_Float16*)ws;                       // 2 x 3145728 f16
  _Float16* Bpack = (_Float16*)(ws + 12582912);
  float* X = (float*)(ws + 25165824);                    // 2 x 64 MiB (dual)

  prep_kernel<<<256, 256, 0, stream>>>(df1, df2, Apack, Bpack);

  const size_t DUAL_NEED = 25165824ull + 2ull * 67108864ull;
  if (ws_size >= DUAL_NEED) {
    // pval/pidx/fidx alias Apack (dead after the dual gemm dispatch)
    float* pval = (float*)Apack;                         // 2 * 238328 f32
    int* pidx = (int*)((char*)Apack + 1906624);
    int* fidx = (int*)((char*)Apack + 3813248);
    gemm_mfma<<<512, 512, 0, stream>>>(Apack, Bpack, X);
    corr_argmax<<<dim3(62, 62, 2), 256, 0, stream>>>(X, pval, pidx, 16777216);
    argmax_reduce<<<32, 256, 0, stream>>>(pval, pidx, pval + 238328, pidx + 238328, fidx);
    flow_kernel<<<576, 256, 0, stream>>>(fidx, out);
  } else {
    // fallback: per-batch sequential (single X buffer)
    float* pval0 = (float*)(ws + 25165824 + 67108864);
    int* pidx0 = (int*)((char*)pval0 + 953312);
    int* fidx = (int*)((char*)pidx0 + 953312);
    float* pval1 = (float*)Apack;                        // dead after gemm(b=1)
    int* pidx1 = (int*)((char*)Apack + 953312);
    gemm_mfma<<<256, 512, 0, stream>>>(Apack, Bpack, X);
    corr_argmax<<<dim3(62, 62, 1), 256, 0, stream>>>(X, pval0, pidx0, 0);
    gemm_mfma<<<256, 512, 0, stream>>>(Apack + 3145728, Bpack + 3145728, X);
    corr_argmax<<<dim3(62, 62, 1), 256, 0, stream>>>(X, pval1, pidx1, 0);
    argmax_reduce<<<32, 256, 0, stream>>>(pval0, pidx0, pval1, pidx1, fidx);
    flow_kernel<<<576, 256, 0, stream>>>(fidx, out);
  }
}